// Round 2
// baseline (778.893 us; speedup 1.0000x reference)
//
#include <hip/hip_runtime.h>
#include <hip/hip_bf16.h>
#include <math.h>

typedef __attribute__((ext_vector_type(8))) __bf16 bh8;   // MFMA A/B frag
typedef __attribute__((ext_vector_type(4))) float  f4;    // MFMA C/D frag

#define NTOK   8192
#define DIM    1024
#define HIDK   2048

// ws layout (bytes)
#define OFF_CNT    0
#define OFF_PSUM   64
#define OFF_OFFS   128
#define OFF_ROWS   512
#define OFF_GATES  (512+262144)
#define OFF_XBF    524800
#define OFF_G      (524800+16777216)          // 16640 x 2048 shorts
#define OFF_W1S    (OFF_G + 68157440)         // 8*4096*1024 shorts (swizzled blobs)
#define OFF_W2S    (OFF_W1S + 67108864)       // 8*1024*2048 shorts

__device__ __forceinline__ unsigned short f2bf(float x){
    union { float f; unsigned u; } v; v.f = x;
    unsigned r = v.u + 0x7FFFu + ((v.u >> 16) & 1u);
    return (unsigned short)(r >> 16);
}
__device__ __forceinline__ unsigned pk2(float a, float b){
    return (unsigned)f2bf(a) | ((unsigned)f2bf(b) << 16);
}
__device__ __forceinline__ void gload_lds16(const void* g, void* l){
    __builtin_amdgcn_global_load_lds((const __attribute__((address_space(1))) void*)g,
                                     (__attribute__((address_space(3))) void*)l, 16, 0, 0);
}

// ---------- x fp32 -> bf16 ----------
__global__ void convert_x(const float* __restrict__ x, short* __restrict__ xbf){
    size_t i = ((size_t)blockIdx.x * 256 + threadIdx.x) * 8;
    const float4* s = (const float4*)(x + i);
    float4 a = s[0], b = s[1];
    uint4 u;
    u.x = pk2(a.x, a.y); u.y = pk2(a.z, a.w);
    u.z = pk2(b.x, b.y); u.w = pk2(b.z, b.w);
    *(uint4*)(xbf + i) = u;
}

// ---------- weights: [e][K][N] fp32 -> swizzled bf16 blobs [e][N/128][K/32][4096 shorts] ----------
// blob slot s (16B) holds col nl=s>>2, k-chunk c = (s&3) ^ (nl&3) ^ ((nl>>2)&3), k = kb*32+c*8+0..7
__global__ void prep_w(const float* __restrict__ W, short* __restrict__ Ws,
                       int Kdim, int Ndim){
    int kb = blockIdx.x, nb = blockIdx.y, e = blockIdx.z;
    int KB = Kdim >> 5, NB = Ndim >> 7;
    __shared__ float tile[32 * 132];   // [k][n], pad 132
    int t = threadIdx.x;
    const float* src = W + ((size_t)(e * Kdim + kb * 32)) * Ndim + (size_t)nb * 128;
    #pragma unroll
    for (int l = 0; l < 4; l++){
        int flat = (l * 256 + t) * 4;
        int k = flat >> 7, n = flat & 127;
        float4 v = *(const float4*)(src + (size_t)k * Ndim + n);
        float* d = &tile[k * 132 + n];
        d[0] = v.x; d[1] = v.y; d[2] = v.z; d[3] = v.w;
    }
    __syncthreads();
    short* dst = Ws + (((size_t)(e * NB + nb)) * KB + kb) * 4096;
    uint out[8];
    #pragma unroll
    for (int sl = 0; sl < 2; sl++){
        int s = t * 2 + sl;
        int nl = s >> 2, pos = s & 3;
        int c = pos ^ (nl & 3) ^ ((nl >> 2) & 3);
        #pragma unroll
        for (int jj = 0; jj < 4; jj++){
            float a = tile[(c * 8 + jj * 2) * 132 + nl];
            float b = tile[(c * 8 + jj * 2 + 1) * 132 + nl];
            out[sl * 4 + jj] = pk2(a, b);
        }
    }
    *(uint4*)(dst + t * 16)     = *(uint4*)&out[0];
    *(uint4*)(dst + t * 16 + 8) = *(uint4*)&out[4];
}

// ---------- router ----------
__global__ void router(const float* __restrict__ x, const float* __restrict__ Wr,
                       const float* __restrict__ br,
                       int* cnt, float* psum, int* rows, float* gates){
    __shared__ float pP[8];
    __shared__ int   tE[32][2];
    __shared__ float tS[32][2];
    __shared__ int   lcnt[8], lpos[64], lexp[64], gbase[8];
    int t = threadIdx.x, lane = t & 63, w = t >> 6;
    if (t < 8){ pP[t] = 0.f; lcnt[t] = 0; }
    __syncthreads();
    int n0 = blockIdx.x * 32 + w * 8;
    for (int tk = 0; tk < 8; tk++){
        int n = n0 + tk;
        float acc[8] = {0,0,0,0,0,0,0,0};
        const float* xr = x + (size_t)n * DIM;
        for (int d = lane; d < DIM; d += 64){
            float xv = xr[d];
            const float* wrow = Wr + d * 8;
            #pragma unroll
            for (int e = 0; e < 8; e++) acc[e] += xv * wrow[e];
        }
        #pragma unroll
        for (int e = 0; e < 8; e++){
            float v = acc[e];
            v += __shfl_xor(v, 32); v += __shfl_xor(v, 16); v += __shfl_xor(v, 8);
            v += __shfl_xor(v, 4);  v += __shfl_xor(v, 2);  v += __shfl_xor(v, 1);
            acc[e] = v;
        }
        if (lane == 0){
            float l[8], ex[8], m = -1e30f;
            #pragma unroll
            for (int e = 0; e < 8; e++){ l[e] = acc[e] + br[e]; m = fmaxf(m, l[e]); }
            float s = 0.f;
            #pragma unroll
            for (int e = 0; e < 8; e++){ ex[e] = expf(l[e] - m); s += ex[e]; }
            float inv = 1.f / s;
            #pragma unroll
            for (int e = 0; e < 8; e++) atomicAdd(&pP[e], ex[e] * inv);
            int i0 = 0; float v0 = l[0];
            #pragma unroll
            for (int e = 1; e < 8; e++) if (l[e] > v0){ v0 = l[e]; i0 = e; }
            int i1 = -1; float v1 = -1e30f;
            #pragma unroll
            for (int e = 0; e < 8; e++) if (e != i0 && l[e] > v1){ v1 = l[e]; i1 = e; }
            float s0 = 1.f / (1.f + expf(v1 - v0));
            int ti = w * 8 + tk;
            tE[ti][0] = i0; tE[ti][1] = i1;
            tS[ti][0] = s0; tS[ti][1] = 1.f - s0;
        }
    }
    __syncthreads();
    if (t < 64){
        int e = tE[t >> 1][t & 1];
        lexp[t] = e;
        lpos[t] = atomicAdd(&lcnt[e], 1);
    }
    __syncthreads();
    if (t < 8){
        gbase[t] = atomicAdd(&cnt[t], lcnt[t]);
        atomicAdd(&psum[t], pP[t]);
    }
    __syncthreads();
    if (t < 64){
        int e = lexp[t];
        int p = gbase[e] + lpos[t];
        int n = blockIdx.x * 32 + (t >> 1);
        rows[e * NTOK + p]  = n;
        gates[e * NTOK + p] = tS[t >> 1][t & 1];
    }
}

__global__ void finalize_aux(const int* cnt, const float* psum, int* offs, float* out_aux){
    if (threadIdx.x == 0){
        int off = 0; float aux = 0.f;
        for (int e = 0; e < 8; e++){
            offs[e] = off; off += cnt[e];
            aux += ((float)cnt[e] * (1.f/8192.f)) * (psum[e] * (1.f/8192.f));
        }
        out_aux[0] = 8.f * aux;
    }
}

// ---------- GEMM1: 128 rows x 64 g-cols, 256 thr, 4 waves ----------
// 2-phase prefetch pipeline (T3 minimum recipe): stage K-step t+1 into buf^1
// BEFORE ds_read+MFMA of buf, single vmcnt(0)+barrier per K-step (the
// __syncthreads at loop bottom). HBM latency overlaps the compute phase.
__global__ __launch_bounds__(256) void gemm1(
    const short* __restrict__ xbf, const short* __restrict__ W1s,
    const float* __restrict__ b1, const int* __restrict__ cnt,
    const int* __restrict__ offs, const int* __restrict__ rows,
    short* __restrict__ g)
{
    int e = blockIdx.z;
    int Me = cnt[e];
    int mbase = blockIdx.y << 7;
    if (mbase >= Me) return;
    int xB = blockIdx.x;                 // 0..31 -> g-cols xB*64
    __shared__ short As [2][128 * 32];   // 16KB (double-buffered)
    __shared__ short Bsa[2][64 * 32];    // 8KB
    __shared__ short Bsb[2][64 * 32];    // 8KB

    int t = threadIdx.x, lane = t & 63, w = t >> 6;
    int wr = w & 1, wc = w >> 1;
    int m = lane & 15, q = lane >> 4;
    int sw8 = (q ^ (m & 3) ^ ((m >> 2) & 3)) << 3;

    const int* rowsE = rows + (e << 13) + mbase;
    int r = t >> 2, pos = t & 3;
    int ca = pos ^ (r & 3) ^ ((r >> 2) & 3);
    int tok0 = (mbase + r      < Me) ? rowsE[r]      : 0;
    int tok1 = (mbase + r + 64 < Me) ? rowsE[r + 64] : 0;
    const short* ga0 = xbf + ((size_t)tok0 << 10) + (ca << 3);
    const short* ga1 = xbf + ((size_t)tok1 << 10) + (ca << 3);
    int ha = xB & 1, nb128 = xB >> 1;
    const short* gb0 = W1s + ((size_t)((e * 32 + nb128)      * 32)) * 4096 + (ha * 256 + t) * 8;
    const short* gb1 = W1s + ((size_t)((e * 32 + 16 + nb128) * 32)) * 4096 + (ha * 256 + t) * 8;

    f4 acc_a[4][2], acc_b[4][2];
    f4 zz = {0.f,0.f,0.f,0.f};
    #pragma unroll
    for (int i = 0; i < 4; i++)
        #pragma unroll
        for (int j = 0; j < 2; j++){ acc_a[i][j] = zz; acc_b[i][j] = zz; }

    // prologue: stage k=0 into buf0
    gload_lds16(ga0, &As [0][w * 512]);
    gload_lds16(ga1, &As [0][2048 + w * 512]);
    gload_lds16(gb0, &Bsa[0][w * 512]);
    gload_lds16(gb1, &Bsb[0][w * 512]);
    ga0 += 32; ga1 += 32; gb0 += 4096; gb1 += 4096;
    __syncthreads();

    int cur = 0;
    #pragma unroll 2
    for (int k0 = 0; k0 < DIM; k0 += 32){
        if (k0 + 32 < DIM){
            int nb = cur ^ 1;
            gload_lds16(ga0, &As [nb][w * 512]);
            gload_lds16(ga1, &As [nb][2048 + w * 512]);
            gload_lds16(gb0, &Bsa[nb][w * 512]);
            gload_lds16(gb1, &Bsb[nb][w * 512]);
            ga0 += 32; ga1 += 32; gb0 += 4096; gb1 += 4096;
        }
        bh8 av[4], ba[2], bb[2];
        #pragma unroll
        for (int i = 0; i < 4; i++)
            av[i] = *(const bh8*)&As[cur][(wr*64 + i*16 + m) * 32 + sw8];
        #pragma unroll
        for (int j = 0; j < 2; j++){
            int nn = ((wc << 5) + j*16 + m) * 32 + sw8;
            ba[j] = *(const bh8*)&Bsa[cur][nn];
            bb[j] = *(const bh8*)&Bsb[cur][nn];
        }
        #pragma unroll
        for (int i = 0; i < 4; i++)
            #pragma unroll
            for (int j = 0; j < 2; j++){
                acc_a[i][j] = __builtin_amdgcn_mfma_f32_16x16x32_bf16(av[i], ba[j], acc_a[i][j], 0, 0, 0);
                acc_b[i][j] = __builtin_amdgcn_mfma_f32_16x16x32_bf16(av[i], bb[j], acc_b[i][j], 0, 0, 0);
            }
        __syncthreads();   // vmcnt(0)+lgkmcnt(0)+barrier: next-tile loads drained here,
        cur ^= 1;          // having overlapped the ds_read+MFMA phase above
    }
    int c0 = xB << 6;
    const float* b1e = b1 + (e << 12);
    int colb = (wc << 5) + m;
    float vba[2], vbb[2];
    #pragma unroll
    for (int j = 0; j < 2; j++){
        vba[j] = b1e[c0 + colb + j*16];
        vbb[j] = b1e[HIDK + c0 + colb + j*16];
    }
    int rb = wr * 64 + (q << 2);
    short* gE = g + ((size_t)(offs[e] + mbase)) * HIDK;
    #pragma unroll
    for (int i = 0; i < 4; i++)
        #pragma unroll
        for (int reg = 0; reg < 4; reg++){
            int mr = rb + i*16 + reg;
            if (mbase + mr < Me){
                short* grow = gE + (size_t)mr * HIDK + c0 + colb;
                #pragma unroll
                for (int j = 0; j < 2; j++){
                    float va = acc_a[i][j][reg] + vba[j];
                    float vb = acc_b[i][j][reg] + vbb[j];
                    grow[j*16] = (short)f2bf(va / (1.f + __expf(-va)) * vb);
                }
            }
        }
}

// ---------- GEMM2: 128 rows x 128 out-cols, 256 thr, 4 waves (wave 64x64) ----------
// same 2-phase prefetch pipeline
__global__ __launch_bounds__(256) void gemm2(
    const short* __restrict__ g, const short* __restrict__ W2s,
    const float* __restrict__ b2, const int* __restrict__ cnt,
    const int* __restrict__ offs, const int* __restrict__ rows,
    const float* __restrict__ gates, float* __restrict__ out)
{
    int e = blockIdx.z;
    int Me = cnt[e];
    int mbase = blockIdx.y << 7;
    if (mbase >= Me) return;
    int db = blockIdx.x;                 // 0..7
    __shared__ short As[2][128 * 32];    // 16KB
    __shared__ short Bs[2][128 * 32];    // 16KB

    int t = threadIdx.x, lane = t & 63, w = t >> 6;
    int wr = w & 1, wc = w >> 1;
    int m = lane & 15, q = lane >> 4;
    int sw8 = (q ^ (m & 3) ^ ((m >> 2) & 3)) << 3;

    int gbaseR = offs[e] + mbase;
    int r = t >> 2;
    int ca = (t & 3) ^ (r & 3) ^ ((r >> 2) & 3);
    const short* ga0 = g + ((size_t)(gbaseR + r))      * HIDK + (ca << 3);
    const short* ga1 = g + ((size_t)(gbaseR + r + 64)) * HIDK + (ca << 3);
    const short* gb0 = W2s + ((size_t)((e * 8 + db) * 64)) * 4096 + t * 8;
    const short* gb1 = gb0 + 2048;       // slots 256..511 (cols 64..127)

    f4 acc[4][4];
    f4 zz = {0.f,0.f,0.f,0.f};
    #pragma unroll
    for (int i = 0; i < 4; i++)
        #pragma unroll
        for (int j = 0; j < 4; j++) acc[i][j] = zz;

    // prologue: stage k=0 into buf0
    gload_lds16(ga0, &As[0][w * 512]);
    gload_lds16(ga1, &As[0][2048 + w * 512]);
    gload_lds16(gb0, &Bs[0][w * 512]);
    gload_lds16(gb1, &Bs[0][2048 + w * 512]);
    ga0 += 32; ga1 += 32; gb0 += 4096; gb1 += 4096;
    __syncthreads();

    int cur = 0;
    #pragma unroll 2
    for (int k0 = 0; k0 < HIDK; k0 += 32){
        if (k0 + 32 < HIDK){
            int nb = cur ^ 1;
            gload_lds16(ga0, &As[nb][w * 512]);
            gload_lds16(ga1, &As[nb][2048 + w * 512]);
            gload_lds16(gb0, &Bs[nb][w * 512]);
            gload_lds16(gb1, &Bs[nb][2048 + w * 512]);
            ga0 += 32; ga1 += 32; gb0 += 4096; gb1 += 4096;
        }
        bh8 av[4], bv[4];
        #pragma unroll
        for (int i = 0; i < 4; i++)
            av[i] = *(const bh8*)&As[cur][(wr*64 + i*16 + m) * 32 + sw8];
        #pragma unroll
        for (int j = 0; j < 4; j++)
            bv[j] = *(const bh8*)&Bs[cur][(wc*64 + j*16 + m) * 32 + sw8];
        #pragma unroll
        for (int i = 0; i < 4; i++)
            #pragma unroll
            for (int j = 0; j < 4; j++)
                acc[i][j] = __builtin_amdgcn_mfma_f32_16x16x32_bf16(av[i], bv[j], acc[i][j], 0, 0, 0);
        __syncthreads();
        cur ^= 1;
    }
    int d0 = db << 7;
    const float* b2e = b2 + (e << 10);
    int colb = wc * 64 + m;
    float vb2[4];
    #pragma unroll
    for (int j = 0; j < 4; j++) vb2[j] = b2e[d0 + colb + j*16];
    const int* rowsE = rows + (e << 13) + mbase;
    const float* gatesE = gates + (e << 13) + mbase;
    int rb = wr * 64 + (q << 2);
    #pragma unroll
    for (int i = 0; i < 4; i++)
        #pragma unroll
        for (int reg = 0; reg < 4; reg++){
            int mr = rb + i*16 + reg;
            if (mbase + mr < Me){
                int token = rowsE[mr];
                float gate = gatesE[mr];
                float* orow = out + ((size_t)token << 10) + d0 + colb;
                #pragma unroll
                for (int j = 0; j < 4; j++)
                    unsafeAtomicAdd(&orow[j*16], gate * (acc[i][j][reg] + vb2[j]));
            }
        }
}

extern "C" void kernel_launch(void* const* d_in, const int* in_sizes, int n_in,
                              void* d_out, int out_size, void* d_ws, size_t ws_size,
                              hipStream_t stream) {
    const float* x  = (const float*)d_in[0];
    const float* Wr = (const float*)d_in[1];
    const float* br = (const float*)d_in[2];
    const float* W1 = (const float*)d_in[3];
    const float* b1 = (const float*)d_in[4];
    const float* W2 = (const float*)d_in[5];
    const float* b2 = (const float*)d_in[6];
    float* out = (float*)d_out;

    char* ws = (char*)d_ws;
    int*   cnt   = (int*)(ws + OFF_CNT);
    float* psum  = (float*)(ws + OFF_PSUM);
    int*   offs  = (int*)(ws + OFF_OFFS);
    int*   rows  = (int*)(ws + OFF_ROWS);
    float* gates = (float*)(ws + OFF_GATES);
    short* xbf   = (short*)(ws + OFF_XBF);
    short* g     = (short*)(ws + OFF_G);
    short* W1s   = (short*)(ws + OFF_W1S);
    short* W2s   = (short*)(ws + OFF_W2S);

    hipMemsetAsync(ws, 0, 192, stream);
    hipMemsetAsync(d_out, 0, (size_t)NTOK * DIM * 4, stream);

    prep_w<<<dim3(32, 32, 8), 256, 0, stream>>>(W1, W1s, 1024, 4096);
    prep_w<<<dim3(64, 8, 8),  256, 0, stream>>>(W2, W2s, 2048, 1024);
    convert_x<<<4096, 256, 0, stream>>>(x, xbf);
    router<<<256, 256, 0, stream>>>(x, Wr, br, cnt, psum, rows, gates);
    finalize_aux<<<1, 64, 0, stream>>>(cnt, psum, offs, out + (size_t)NTOK * DIM);
    gemm1<<<dim3(32, 64, 8), 256, 0, stream>>>(xbf, W1s, b1, cnt, offs, rows, g);
    gemm2<<<dim3(8, 64, 8),  256, 0, stream>>>(g, W2s, b2, cnt, offs, rows, gates, out);
}

// Round 5
// 718.532 us; speedup vs baseline: 1.0840x; 1.0840x over previous
//
#include <hip/hip_runtime.h>
#include <hip/hip_bf16.h>
#include <math.h>

typedef __attribute__((ext_vector_type(8))) __bf16 bh8;   // MFMA A/B frag
typedef __attribute__((ext_vector_type(4))) float  f4;    // MFMA C/D frag

#define NTOK   8192
#define DIM    1024
#define HIDK   2048

// ws layout (bytes)
#define OFF_CNT    0
#define OFF_PSUM   64
#define OFF_OFFS   128
#define OFF_ROWS   512
#define OFF_GATES  (512+262144)
#define OFF_XBF    524800
#define OFF_G      (524800+16777216)          // 16640 x 2048 shorts
#define OFF_W1S    (OFF_G + 68157440)         // 8*4096*1024 shorts (swizzled blobs)
#define OFF_W2S    (OFF_W1S + 67108864)       // 8*1024*2048 shorts

__device__ __forceinline__ unsigned short f2bf(float x){
    union { float f; unsigned u; } v; v.f = x;
    unsigned r = v.u + 0x7FFFu + ((v.u >> 16) & 1u);
    return (unsigned short)(r >> 16);
}
__device__ __forceinline__ unsigned pk2(float a, float b){
    return (unsigned)f2bf(a) | ((unsigned)f2bf(b) << 16);
}
__device__ __forceinline__ void gload_lds16(const void* g, void* l){
    __builtin_amdgcn_global_load_lds((const __attribute__((address_space(1))) void*)g,
                                     (__attribute__((address_space(3))) void*)l, 16, 0, 0);
}

// ---------- x fp32 -> bf16 ----------
__global__ void convert_x(const float* __restrict__ x, short* __restrict__ xbf){
    size_t i = ((size_t)blockIdx.x * 256 + threadIdx.x) * 8;
    const float4* s = (const float4*)(x + i);
    float4 a = s[0], b = s[1];
    uint4 u;
    u.x = pk2(a.x, a.y); u.y = pk2(a.z, a.w);
    u.z = pk2(b.x, b.y); u.w = pk2(b.z, b.w);
    *(uint4*)(xbf + i) = u;
}

// ---------- weights: [e][K][N] fp32 -> swizzled bf16 blobs [e][N/128][K/32][4096 shorts] ----------
// blob slot s (16B) holds col nl=s>>2, k-chunk c = (s&3) ^ (nl&3) ^ ((nl>>2)&3), k = kb*32+c*8+0..7
__global__ void prep_w(const float* __restrict__ W, short* __restrict__ Ws,
                       int Kdim, int Ndim){
    int kb = blockIdx.x, nb = blockIdx.y, e = blockIdx.z;
    int KB = Kdim >> 5, NB = Ndim >> 7;
    __shared__ float tile[32 * 132];   // [k][n], pad 132
    int t = threadIdx.x;
    const float* src = W + ((size_t)(e * Kdim + kb * 32)) * Ndim + (size_t)nb * 128;
    #pragma unroll
    for (int l = 0; l < 4; l++){
        int flat = (l * 256 + t) * 4;
        int k = flat >> 7, n = flat & 127;
        float4 v = *(const float4*)(src + (size_t)k * Ndim + n);
        float* d = &tile[k * 132 + n];
        d[0] = v.x; d[1] = v.y; d[2] = v.z; d[3] = v.w;
    }
    __syncthreads();
    short* dst = Ws + (((size_t)(e * NB + nb)) * KB + kb) * 4096;
    uint out[8];
    #pragma unroll
    for (int sl = 0; sl < 2; sl++){
        int s = t * 2 + sl;
        int nl = s >> 2, pos = s & 3;
        int c = pos ^ (nl & 3) ^ ((nl >> 2) & 3);
        #pragma unroll
        for (int jj = 0; jj < 4; jj++){
            float a = tile[(c * 8 + jj * 2) * 132 + nl];
            float b = tile[(c * 8 + jj * 2 + 1) * 132 + nl];
            out[sl * 4 + jj] = pk2(a, b);
        }
    }
    *(uint4*)(dst + t * 16)     = *(uint4*)&out[0];
    *(uint4*)(dst + t * 16 + 8) = *(uint4*)&out[4];
}

// ---------- router ----------
__global__ void router(const float* __restrict__ x, const float* __restrict__ Wr,
                       const float* __restrict__ br,
                       int* cnt, float* psum, int* rows, float* gates){
    __shared__ float pP[8];
    __shared__ int   tE[32][2];
    __shared__ float tS[32][2];
    __shared__ int   lcnt[8], lpos[64], lexp[64], gbase[8];
    int t = threadIdx.x, lane = t & 63, w = t >> 6;
    if (t < 8){ pP[t] = 0.f; lcnt[t] = 0; }
    __syncthreads();
    int n0 = blockIdx.x * 32 + w * 8;
    for (int tk = 0; tk < 8; tk++){
        int n = n0 + tk;
        float acc[8] = {0,0,0,0,0,0,0,0};
        const float* xr = x + (size_t)n * DIM;
        for (int d = lane; d < DIM; d += 64){
            float xv = xr[d];
            const float* wrow = Wr + d * 8;
            #pragma unroll
            for (int e = 0; e < 8; e++) acc[e] += xv * wrow[e];
        }
        #pragma unroll
        for (int e = 0; e < 8; e++){
            float v = acc[e];
            v += __shfl_xor(v, 32); v += __shfl_xor(v, 16); v += __shfl_xor(v, 8);
            v += __shfl_xor(v, 4);  v += __shfl_xor(v, 2);  v += __shfl_xor(v, 1);
            acc[e] = v;
        }
        if (lane == 0){
            float l[8], ex[8], m = -1e30f;
            #pragma unroll
            for (int e = 0; e < 8; e++){ l[e] = acc[e] + br[e]; m = fmaxf(m, l[e]); }
            float s = 0.f;
            #pragma unroll
            for (int e = 0; e < 8; e++){ ex[e] = expf(l[e] - m); s += ex[e]; }
            float inv = 1.f / s;
            #pragma unroll
            for (int e = 0; e < 8; e++) atomicAdd(&pP[e], ex[e] * inv);
            int i0 = 0; float v0 = l[0];
            #pragma unroll
            for (int e = 1; e < 8; e++) if (l[e] > v0){ v0 = l[e]; i0 = e; }
            int i1 = -1; float v1 = -1e30f;
            #pragma unroll
            for (int e = 0; e < 8; e++) if (e != i0 && l[e] > v1){ v1 = l[e]; i1 = e; }
            float s0 = 1.f / (1.f + expf(v1 - v0));
            int ti = w * 8 + tk;
            tE[ti][0] = i0; tE[ti][1] = i1;
            tS[ti][0] = s0; tS[ti][1] = 1.f - s0;
        }
    }
    __syncthreads();
    if (t < 64){
        int e = tE[t >> 1][t & 1];
        lexp[t] = e;
        lpos[t] = atomicAdd(&lcnt[e], 1);
    }
    __syncthreads();
    if (t < 8){
        gbase[t] = atomicAdd(&cnt[t], lcnt[t]);
        atomicAdd(&psum[t], pP[t]);
    }
    __syncthreads();
    if (t < 64){
        int e = lexp[t];
        int p = gbase[e] + lpos[t];
        int n = blockIdx.x * 32 + (t >> 1);
        rows[e * NTOK + p]  = n;
        gates[e * NTOK + p] = tS[t >> 1][t & 1];
    }
}

__global__ void finalize_aux(const int* cnt, const float* psum, int* offs, float* out_aux){
    if (threadIdx.x == 0){
        int off = 0; float aux = 0.f;
        for (int e = 0; e < 8; e++){
            offs[e] = off; off += cnt[e];
            aux += ((float)cnt[e] * (1.f/8192.f)) * (psum[e] * (1.f/8192.f));
        }
        out_aux[0] = 8.f * aux;
    }
}

// ---------- GEMM1: 128 rows x 64 g-cols (64 a-cols + 64 b-cols), 256 thr, 4 waves ----------
// Baseline m97-style sync skeleton (stage -> barrier/drain -> compute -> barrier),
// but BK=64: each drain amortizes 32 MFMA/wave instead of 16 (half the drains/barriers).
// LDS 32KB single-buffered; residency is register-capped so no occupancy loss expected.
__global__ __launch_bounds__(256) void gemm1(
    const short* __restrict__ xbf, const short* __restrict__ W1s,
    const float* __restrict__ b1, const int* __restrict__ cnt,
    const int* __restrict__ offs, const int* __restrict__ rows,
    short* __restrict__ g)
{
    int e = blockIdx.z;
    int Me = cnt[e];
    int mbase = blockIdx.y << 7;
    if (mbase >= Me) return;
    int xB = blockIdx.x;                 // 0..31 -> g-cols xB*64
    __shared__ short As [2][128 * 32];   // [k-chunk][row*32 + slot*8]  16KB
    __shared__ short Bsa[2][64 * 32];    // 8KB
    __shared__ short Bsb[2][64 * 32];    // 8KB

    int t = threadIdx.x, lane = t & 63, w = t >> 6;
    int wr = w & 1, wc = w >> 1;
    int m = lane & 15, q = lane >> 4;
    int sw8 = (q ^ (m & 3) ^ ((m >> 2) & 3)) << 3;

    const int* rowsE = rows + (e << 13) + mbase;
    int r = t >> 2, pos = t & 3;
    int ca = pos ^ (r & 3) ^ ((r >> 2) & 3);
    int tok0 = (mbase + r      < Me) ? rowsE[r]      : 0;
    int tok1 = (mbase + r + 64 < Me) ? rowsE[r + 64] : 0;
    const short* ga0 = xbf + ((size_t)tok0 << 10) + (ca << 3);
    const short* ga1 = xbf + ((size_t)tok1 << 10) + (ca << 3);
    int ha = xB & 1, nb128 = xB >> 1;
    const short* gb0 = W1s + ((size_t)((e * 32 + nb128)      * 32)) * 4096 + (ha * 256 + t) * 8;
    const short* gb1 = W1s + ((size_t)((e * 32 + 16 + nb128) * 32)) * 4096 + (ha * 256 + t) * 8;

    f4 acc_a[4][2], acc_b[4][2];
    f4 zz = {0.f,0.f,0.f,0.f};
    #pragma unroll
    for (int i = 0; i < 4; i++)
        #pragma unroll
        for (int j = 0; j < 2; j++){ acc_a[i][j] = zz; acc_b[i][j] = zz; }

    for (int k0 = 0; k0 < DIM; k0 += 64){
        __syncthreads();
        // stage both 32-k chunks of this 64-K step (8 x 16B per thread)
        gload_lds16(ga0,        &As [0][w * 512]);
        gload_lds16(ga0 + 32,   &As [1][w * 512]);
        gload_lds16(ga1,        &As [0][2048 + w * 512]);
        gload_lds16(ga1 + 32,   &As [1][2048 + w * 512]);
        gload_lds16(gb0,        &Bsa[0][w * 512]);
        gload_lds16(gb0 + 4096, &Bsa[1][w * 512]);
        gload_lds16(gb1,        &Bsb[0][w * 512]);
        gload_lds16(gb1 + 4096, &Bsb[1][w * 512]);
        ga0 += 64; ga1 += 64; gb0 += 8192; gb1 += 8192;
        __syncthreads();
        #pragma unroll
        for (int c2 = 0; c2 < 2; c2++){
            bh8 av[4], ba[2], bb[2];
            #pragma unroll
            for (int i = 0; i < 4; i++)
                av[i] = *(const bh8*)&As[c2][(wr*64 + i*16 + m) * 32 + sw8];
            #pragma unroll
            for (int j = 0; j < 2; j++){
                int nn = ((wc << 5) + j*16 + m) * 32 + sw8;
                ba[j] = *(const bh8*)&Bsa[c2][nn];
                bb[j] = *(const bh8*)&Bsb[c2][nn];
            }
            #pragma unroll
            for (int i = 0; i < 4; i++)
                #pragma unroll
                for (int j = 0; j < 2; j++){
                    acc_a[i][j] = __builtin_amdgcn_mfma_f32_16x16x32_bf16(av[i], ba[j], acc_a[i][j], 0, 0, 0);
                    acc_b[i][j] = __builtin_amdgcn_mfma_f32_16x16x32_bf16(av[i], bb[j], acc_b[i][j], 0, 0, 0);
                }
        }
    }
    int c0 = xB << 6;
    const float* b1e = b1 + (e << 12);
    int colb = (wc << 5) + m;
    float vba[2], vbb[2];
    #pragma unroll
    for (int j = 0; j < 2; j++){
        vba[j] = b1e[c0 + colb + j*16];
        vbb[j] = b1e[HIDK + c0 + colb + j*16];
    }
    int rb = wr * 64 + (q << 2);
    short* gE = g + ((size_t)(offs[e] + mbase)) * HIDK;
    #pragma unroll
    for (int i = 0; i < 4; i++)
        #pragma unroll
        for (int reg = 0; reg < 4; reg++){
            int mr = rb + i*16 + reg;
            if (mbase + mr < Me){
                short* grow = gE + (size_t)mr * HIDK + c0 + colb;
                #pragma unroll
                for (int j = 0; j < 2; j++){
                    float va = acc_a[i][j][reg] + vba[j];
                    float vb = acc_b[i][j][reg] + vbb[j];
                    grow[j*16] = (short)f2bf(va / (1.f + __expf(-va)) * vb);
                }
            }
        }
}

// ---------- GEMM2: 128 rows x 128 out-cols, 256 thr, 4 waves (wave 64x64) ----------
// same BK=64 single-buffer skeleton
__global__ __launch_bounds__(256) void gemm2(
    const short* __restrict__ g, const short* __restrict__ W2s,
    const float* __restrict__ b2, const int* __restrict__ cnt,
    const int* __restrict__ offs, const int* __restrict__ rows,
    const float* __restrict__ gates, float* __restrict__ out)
{
    int e = blockIdx.z;
    int Me = cnt[e];
    int mbase = blockIdx.y << 7;
    if (mbase >= Me) return;
    int db = blockIdx.x;                 // 0..7
    __shared__ short As[2][128 * 32];    // 16KB
    __shared__ short Bs[2][128 * 32];    // 16KB

    int t = threadIdx.x, lane = t & 63, w = t >> 6;
    int wr = w & 1, wc = w >> 1;
    int m = lane & 15, q = lane >> 4;
    int sw8 = (q ^ (m & 3) ^ ((m >> 2) & 3)) << 3;

    int gbaseR = offs[e] + mbase;
    int r = t >> 2;
    int ca = (t & 3) ^ (r & 3) ^ ((r >> 2) & 3);
    const short* ga0 = g + ((size_t)(gbaseR + r))      * HIDK + (ca << 3);
    const short* ga1 = g + ((size_t)(gbaseR + r + 64)) * HIDK + (ca << 3);
    const short* gb0 = W2s + ((size_t)((e * 8 + db) * 64)) * 4096 + t * 8;
    const short* gb1 = gb0 + 2048;       // slots 256..511 (cols 64..127)

    f4 acc[4][4];
    f4 zz = {0.f,0.f,0.f,0.f};
    #pragma unroll
    for (int i = 0; i < 4; i++)
        #pragma unroll
        for (int j = 0; j < 4; j++) acc[i][j] = zz;

    for (int k0 = 0; k0 < HIDK; k0 += 64){
        __syncthreads();
        gload_lds16(ga0,        &As[0][w * 512]);
        gload_lds16(ga0 + 32,   &As[1][w * 512]);
        gload_lds16(ga1,        &As[0][2048 + w * 512]);
        gload_lds16(ga1 + 32,   &As[1][2048 + w * 512]);
        gload_lds16(gb0,        &Bs[0][w * 512]);
        gload_lds16(gb0 + 4096, &Bs[1][w * 512]);
        gload_lds16(gb1,        &Bs[0][2048 + w * 512]);
        gload_lds16(gb1 + 4096, &Bs[1][2048 + w * 512]);
        ga0 += 64; ga1 += 64; gb0 += 8192; gb1 += 8192;
        __syncthreads();
        #pragma unroll
        for (int c2 = 0; c2 < 2; c2++){
            bh8 av[4], bv[4];
            #pragma unroll
            for (int i = 0; i < 4; i++)
                av[i] = *(const bh8*)&As[c2][(wr*64 + i*16 + m) * 32 + sw8];
            #pragma unroll
            for (int j = 0; j < 4; j++)
                bv[j] = *(const bh8*)&Bs[c2][(wc*64 + j*16 + m) * 32 + sw8];
            #pragma unroll
            for (int i = 0; i < 4; i++)
                #pragma unroll
                for (int j = 0; j < 4; j++)
                    acc[i][j] = __builtin_amdgcn_mfma_f32_16x16x32_bf16(av[i], bv[j], acc[i][j], 0, 0, 0);
        }
    }
    int d0 = db << 7;
    const float* b2e = b2 + (e << 10);
    int colb = wc * 64 + m;
    float vb2[4];
    #pragma unroll
    for (int j = 0; j < 4; j++) vb2[j] = b2e[d0 + colb + j*16];
    const int* rowsE = rows + (e << 13) + mbase;
    const float* gatesE = gates + (e << 13) + mbase;
    int rb = wr * 64 + (q << 2);
    #pragma unroll
    for (int i = 0; i < 4; i++)
        #pragma unroll
        for (int reg = 0; reg < 4; reg++){
            int mr = rb + i*16 + reg;
            if (mbase + mr < Me){
                int token = rowsE[mr];
                float gate = gatesE[mr];
                float* orow = out + ((size_t)token << 10) + d0 + colb;
                #pragma unroll
                for (int j = 0; j < 4; j++)
                    unsafeAtomicAdd(&orow[j*16], gate * (acc[i][j][reg] + vb2[j]));
            }
        }
}

extern "C" void kernel_launch(void* const* d_in, const int* in_sizes, int n_in,
                              void* d_out, int out_size, void* d_ws, size_t ws_size,
                              hipStream_t stream) {
    const float* x  = (const float*)d_in[0];
    const float* Wr = (const float*)d_in[1];
    const float* br = (const float*)d_in[2];
    const float* W1 = (const float*)d_in[3];
    const float* b1 = (const float*)d_in[4];
    const float* W2 = (const float*)d_in[5];
    const float* b2 = (const float*)d_in[6];
    float* out = (float*)d_out;

    char* ws = (char*)d_ws;
    int*   cnt   = (int*)(ws + OFF_CNT);
    float* psum  = (float*)(ws + OFF_PSUM);
    int*   offs  = (int*)(ws + OFF_OFFS);
    int*   rows  = (int*)(ws + OFF_ROWS);
    float* gates = (float*)(ws + OFF_GATES);
    short* xbf   = (short*)(ws + OFF_XBF);
    short* g     = (short*)(ws + OFF_G);
    short* W1s   = (short*)(ws + OFF_W1S);
    short* W2s   = (short*)(ws + OFF_W2S);

    hipMemsetAsync(ws, 0, 192, stream);
    hipMemsetAsync(d_out, 0, (size_t)NTOK * DIM * 4, stream);

    prep_w<<<dim3(32, 32, 8), 256, 0, stream>>>(W1, W1s, 1024, 4096);
    prep_w<<<dim3(64, 8, 8),  256, 0, stream>>>(W2, W2s, 2048, 1024);
    convert_x<<<4096, 256, 0, stream>>>(x, xbf);
    router<<<256, 256, 0, stream>>>(x, Wr, br, cnt, psum, rows, gates);
    finalize_aux<<<1, 64, 0, stream>>>(cnt, psum, offs, out + (size_t)NTOK * DIM);
    gemm1<<<dim3(32, 64, 8), 256, 0, stream>>>(xbf, W1s, b1, cnt, offs, rows, g);
    gemm2<<<dim3(8, 64, 8),  256, 0, stream>>>(g, W2s, b2, cnt, offs, rows, gates, out);
}

// Round 7
// 673.887 us; speedup vs baseline: 1.1558x; 1.0662x over previous
//
#include <hip/hip_runtime.h>
#include <hip/hip_bf16.h>
#include <math.h>

typedef __attribute__((ext_vector_type(8))) __bf16 bh8;   // MFMA A/B frag
typedef __attribute__((ext_vector_type(4))) float  f4;    // MFMA C/D frag

#define NTOK   8192
#define DIM    1024
#define HIDK   2048

// ws layout (bytes)
#define OFF_CNT    0
#define OFF_PSUM   64
#define OFF_OFFS   128
#define OFF_ROWS   512
#define OFF_GATES  (512+262144)
#define OFF_XBF    524800
#define OFF_G      (524800+16777216)          // 16640 x 2048 shorts
#define OFF_W1S    (OFF_G + 68157440)         // 8*4096*1024 shorts (swizzled blobs)
#define OFF_W2S    (OFF_W1S + 67108864)       // 8*1024*2048 shorts

__device__ __forceinline__ unsigned short f2bf(float x){
    union { float f; unsigned u; } v; v.f = x;
    unsigned r = v.u + 0x7FFFu + ((v.u >> 16) & 1u);
    return (unsigned short)(r >> 16);
}
__device__ __forceinline__ unsigned pk2(float a, float b){
    return (unsigned)f2bf(a) | ((unsigned)f2bf(b) << 16);
}
__device__ __forceinline__ void gload_lds16(const void* g, void* l){
    __builtin_amdgcn_global_load_lds((const __attribute__((address_space(1))) void*)g,
                                     (__attribute__((address_space(3))) void*)l, 16, 0, 0);
}

// ---------- x fp32 -> bf16 ----------
__global__ void convert_x(const float* __restrict__ x, short* __restrict__ xbf){
    size_t i = ((size_t)blockIdx.x * 256 + threadIdx.x) * 8;
    const float4* s = (const float4*)(x + i);
    float4 a = s[0], b = s[1];
    uint4 u;
    u.x = pk2(a.x, a.y); u.y = pk2(a.z, a.w);
    u.z = pk2(b.x, b.y); u.w = pk2(b.z, b.w);
    *(uint4*)(xbf + i) = u;
}

// ---------- weights: [e][K][N] fp32 -> swizzled bf16 blobs [e][N/128][K/32][4096 shorts] ----------
// blob slot s (16B) holds col nl=s>>2, k-chunk c = (s&3) ^ (nl&3) ^ ((nl>>2)&3), k = kb*32+c*8+0..7
__global__ void prep_w(const float* __restrict__ W, short* __restrict__ Ws,
                       int Kdim, int Ndim){
    int kb = blockIdx.x, nb = blockIdx.y, e = blockIdx.z;
    int KB = Kdim >> 5, NB = Ndim >> 7;
    __shared__ float tile[32 * 132];   // [k][n], pad 132
    int t = threadIdx.x;
    const float* src = W + ((size_t)(e * Kdim + kb * 32)) * Ndim + (size_t)nb * 128;
    #pragma unroll
    for (int l = 0; l < 4; l++){
        int flat = (l * 256 + t) * 4;
        int k = flat >> 7, n = flat & 127;
        float4 v = *(const float4*)(src + (size_t)k * Ndim + n);
        float* d = &tile[k * 132 + n];
        d[0] = v.x; d[1] = v.y; d[2] = v.z; d[3] = v.w;
    }
    __syncthreads();
    short* dst = Ws + (((size_t)(e * NB + nb)) * KB + kb) * 4096;
    uint out[8];
    #pragma unroll
    for (int sl = 0; sl < 2; sl++){
        int s = t * 2 + sl;
        int nl = s >> 2, pos = s & 3;
        int c = pos ^ (nl & 3) ^ ((nl >> 2) & 3);
        #pragma unroll
        for (int jj = 0; jj < 4; jj++){
            float a = tile[(c * 8 + jj * 2) * 132 + nl];
            float b = tile[(c * 8 + jj * 2 + 1) * 132 + nl];
            out[sl * 4 + jj] = pk2(a, b);
        }
    }
    *(uint4*)(dst + t * 16)     = *(uint4*)&out[0];
    *(uint4*)(dst + t * 16 + 8) = *(uint4*)&out[4];
}

// ---------- router ----------
__global__ void router(const float* __restrict__ x, const float* __restrict__ Wr,
                       const float* __restrict__ br,
                       int* cnt, float* psum, int* rows, float* gates){
    __shared__ float pP[8];
    __shared__ int   tE[32][2];
    __shared__ float tS[32][2];
    __shared__ int   lcnt[8], lpos[64], lexp[64], gbase[8];
    int t = threadIdx.x, lane = t & 63, w = t >> 6;
    if (t < 8){ pP[t] = 0.f; lcnt[t] = 0; }
    __syncthreads();
    int n0 = blockIdx.x * 32 + w * 8;
    for (int tk = 0; tk < 8; tk++){
        int n = n0 + tk;
        float acc[8] = {0,0,0,0,0,0,0,0};
        const float* xr = x + (size_t)n * DIM;
        for (int d = lane; d < DIM; d += 64){
            float xv = xr[d];
            const float* wrow = Wr + d * 8;
            #pragma unroll
            for (int e = 0; e < 8; e++) acc[e] += xv * wrow[e];
        }
        #pragma unroll
        for (int e = 0; e < 8; e++){
            float v = acc[e];
            v += __shfl_xor(v, 32); v += __shfl_xor(v, 16); v += __shfl_xor(v, 8);
            v += __shfl_xor(v, 4);  v += __shfl_xor(v, 2);  v += __shfl_xor(v, 1);
            acc[e] = v;
        }
        if (lane == 0){
            float l[8], ex[8], m = -1e30f;
            #pragma unroll
            for (int e = 0; e < 8; e++){ l[e] = acc[e] + br[e]; m = fmaxf(m, l[e]); }
            float s = 0.f;
            #pragma unroll
            for (int e = 0; e < 8; e++){ ex[e] = expf(l[e] - m); s += ex[e]; }
            float inv = 1.f / s;
            #pragma unroll
            for (int e = 0; e < 8; e++) atomicAdd(&pP[e], ex[e] * inv);
            int i0 = 0; float v0 = l[0];
            #pragma unroll
            for (int e = 1; e < 8; e++) if (l[e] > v0){ v0 = l[e]; i0 = e; }
            int i1 = -1; float v1 = -1e30f;
            #pragma unroll
            for (int e = 0; e < 8; e++) if (e != i0 && l[e] > v1){ v1 = l[e]; i1 = e; }
            float s0 = 1.f / (1.f + expf(v1 - v0));
            int ti = w * 8 + tk;
            tE[ti][0] = i0; tE[ti][1] = i1;
            tS[ti][0] = s0; tS[ti][1] = 1.f - s0;
        }
    }
    __syncthreads();
    if (t < 64){
        int e = tE[t >> 1][t & 1];
        lexp[t] = e;
        lpos[t] = atomicAdd(&lcnt[e], 1);
    }
    __syncthreads();
    if (t < 8){
        gbase[t] = atomicAdd(&cnt[t], lcnt[t]);
        atomicAdd(&psum[t], pP[t]);
    }
    __syncthreads();
    if (t < 64){
        int e = lexp[t];
        int p = gbase[e] + lpos[t];
        int n = blockIdx.x * 32 + (t >> 1);
        rows[e * NTOK + p]  = n;
        gates[e * NTOK + p] = tS[t >> 1][t & 1];
    }
}

__global__ void finalize_aux(const int* cnt, const float* psum, int* offs, float* out_aux){
    if (threadIdx.x == 0){
        int off = 0; float aux = 0.f;
        for (int e = 0; e < 8; e++){
            offs[e] = off; off += cnt[e];
            aux += ((float)cnt[e] * (1.f/8192.f)) * (psum[e] * (1.f/8192.f));
        }
        out_aux[0] = 8.f * aux;
    }
}

// ---------- GEMM1: 128 rows x 64 g-cols (64 a-cols + 64 b-cols), 256 thr, 4 waves ----------
// Verified baseline skeleton (16KB LDS, BK=32, 2 barriers/step).
// __launch_bounds__(256, 4): cap unified VGPR+AGPR at 128/thread -> 4 blocks/CU
// (baseline was 140 regs -> 3 blocks/CU, occupancy 31%). Inter-block overlap is
// what hides the staging drain; +1 resident block = +33% TLP.
__global__ __launch_bounds__(256, 4) void gemm1(
    const short* __restrict__ xbf, const short* __restrict__ W1s,
    const float* __restrict__ b1, const int* __restrict__ cnt,
    const int* __restrict__ offs, const int* __restrict__ rows,
    short* __restrict__ g)
{
    int e = blockIdx.z;
    int Me = cnt[e];
    int mbase = blockIdx.y << 7;
    if (mbase >= Me) return;
    int xB = blockIdx.x;                 // 0..31 -> g-cols xB*64
    __shared__ short As[128 * 32];       // 8KB
    __shared__ short Bsa[64 * 32];       // 4KB
    __shared__ short Bsb[64 * 32];       // 4KB

    int t = threadIdx.x, lane = t & 63, w = t >> 6;
    int wr = w & 1, wc = w >> 1;
    int m = lane & 15, q = lane >> 4;
    int sw8 = (q ^ (m & 3) ^ ((m >> 2) & 3)) << 3;

    const int* rowsE = rows + (e << 13) + mbase;
    int r = t >> 2, pos = t & 3;
    int ca = pos ^ (r & 3) ^ ((r >> 2) & 3);
    int tok0 = (mbase + r      < Me) ? rowsE[r]      : 0;
    int tok1 = (mbase + r + 64 < Me) ? rowsE[r + 64] : 0;
    const short* ga0 = xbf + ((size_t)tok0 << 10) + (ca << 3);
    const short* ga1 = xbf + ((size_t)tok1 << 10) + (ca << 3);
    int ha = xB & 1, nb128 = xB >> 1;
    const short* gb0 = W1s + ((size_t)((e * 32 + nb128)      * 32)) * 4096 + (ha * 256 + t) * 8;
    const short* gb1 = W1s + ((size_t)((e * 32 + 16 + nb128) * 32)) * 4096 + (ha * 256 + t) * 8;
    short* ldsA0 = As  + w * 512;            // slots w*64..w*64+63 (rows 0..63)
    short* ldsA1 = As  + 2048 + w * 512;     // rows 64..127
    short* ldsBa = Bsa + w * 512;
    short* ldsBb = Bsb + w * 512;

    f4 acc_a[4][2], acc_b[4][2];
    f4 zz = {0.f,0.f,0.f,0.f};
    #pragma unroll
    for (int i = 0; i < 4; i++)
        #pragma unroll
        for (int j = 0; j < 2; j++){ acc_a[i][j] = zz; acc_b[i][j] = zz; }

    for (int k0 = 0; k0 < DIM; k0 += 32){
        __syncthreads();
        gload_lds16(ga0, ldsA0);
        gload_lds16(ga1, ldsA1);
        gload_lds16(gb0, ldsBa);
        gload_lds16(gb1, ldsBb);
        ga0 += 32; ga1 += 32; gb0 += 4096; gb1 += 4096;
        __syncthreads();
        bh8 av[4], ba[2], bb[2];
        #pragma unroll
        for (int i = 0; i < 4; i++)
            av[i] = *(const bh8*)&As[(wr*64 + i*16 + m) * 32 + sw8];
        #pragma unroll
        for (int j = 0; j < 2; j++){
            int nn = ((wc << 5) + j*16 + m) * 32 + sw8;
            ba[j] = *(const bh8*)&Bsa[nn];
            bb[j] = *(const bh8*)&Bsb[nn];
        }
        #pragma unroll
        for (int i = 0; i < 4; i++)
            #pragma unroll
            for (int j = 0; j < 2; j++){
                acc_a[i][j] = __builtin_amdgcn_mfma_f32_16x16x32_bf16(av[i], ba[j], acc_a[i][j], 0, 0, 0);
                acc_b[i][j] = __builtin_amdgcn_mfma_f32_16x16x32_bf16(av[i], bb[j], acc_b[i][j], 0, 0, 0);
            }
    }
    int c0 = xB << 6;
    const float* b1e = b1 + (e << 12);
    int colb = (wc << 5) + m;
    float vba[2], vbb[2];
    #pragma unroll
    for (int j = 0; j < 2; j++){
        vba[j] = b1e[c0 + colb + j*16];
        vbb[j] = b1e[HIDK + c0 + colb + j*16];
    }
    int rb = wr * 64 + (q << 2);
    short* gE = g + ((size_t)(offs[e] + mbase)) * HIDK;
    #pragma unroll
    for (int i = 0; i < 4; i++)
        #pragma unroll
        for (int reg = 0; reg < 4; reg++){
            int mr = rb + i*16 + reg;
            if (mbase + mr < Me){
                short* grow = gE + (size_t)mr * HIDK + c0 + colb;
                #pragma unroll
                for (int j = 0; j < 2; j++){
                    float va = acc_a[i][j][reg] + vba[j];
                    float vb = acc_b[i][j][reg] + vbb[j];
                    grow[j*16] = (short)f2bf(va / (1.f + __expf(-va)) * vb);
                }
            }
        }
}

// ---------- GEMM2: 128 rows x 128 out-cols, 256 thr, 4 waves (wave 64x64) ----------
// same skeleton + 128-reg cap for 4 blocks/CU
__global__ __launch_bounds__(256, 4) void gemm2(
    const short* __restrict__ g, const short* __restrict__ W2s,
    const float* __restrict__ b2, const int* __restrict__ cnt,
    const int* __restrict__ offs, const int* __restrict__ rows,
    const float* __restrict__ gates, float* __restrict__ out)
{
    int e = blockIdx.z;
    int Me = cnt[e];
    int mbase = blockIdx.y << 7;
    if (mbase >= Me) return;
    int db = blockIdx.x;                 // 0..7
    __shared__ short As[128 * 32];       // 8KB
    __shared__ short Bs[128 * 32];       // 8KB

    int t = threadIdx.x, lane = t & 63, w = t >> 6;
    int wr = w & 1, wc = w >> 1;
    int m = lane & 15, q = lane >> 4;
    int sw8 = (q ^ (m & 3) ^ ((m >> 2) & 3)) << 3;

    int gbaseR = offs[e] + mbase;
    int r = t >> 2;
    int ca = (t & 3) ^ (r & 3) ^ ((r >> 2) & 3);
    const short* ga0 = g + ((size_t)(gbaseR + r))      * HIDK + (ca << 3);
    const short* ga1 = g + ((size_t)(gbaseR + r + 64)) * HIDK + (ca << 3);
    const short* gb0 = W2s + ((size_t)((e * 8 + db) * 64)) * 4096 + t * 8;
    const short* gb1 = gb0 + 2048;       // slots 256..511 (cols 64..127)
    short* ldsA0 = As + w * 512;
    short* ldsA1 = As + 2048 + w * 512;
    short* ldsB0 = Bs + w * 512;
    short* ldsB1 = Bs + 2048 + w * 512;

    f4 acc[4][4];
    f4 zz = {0.f,0.f,0.f,0.f};
    #pragma unroll
    for (int i = 0; i < 4; i++)
        #pragma unroll
        for (int j = 0; j < 4; j++) acc[i][j] = zz;

    for (int k0 = 0; k0 < HIDK; k0 += 32){
        __syncthreads();
        gload_lds16(ga0, ldsA0);
        gload_lds16(ga1, ldsA1);
        gload_lds16(gb0, ldsB0);
        gload_lds16(gb1, ldsB1);
        ga0 += 32; ga1 += 32; gb0 += 4096; gb1 += 4096;
        __syncthreads();
        bh8 av[4], bv[4];
        #pragma unroll
        for (int i = 0; i < 4; i++)
            av[i] = *(const bh8*)&As[(wr*64 + i*16 + m) * 32 + sw8];
        #pragma unroll
        for (int j = 0; j < 4; j++)
            bv[j] = *(const bh8*)&Bs[(wc*64 + j*16 + m) * 32 + sw8];
        #pragma unroll
        for (int i = 0; i < 4; i++)
            #pragma unroll
            for (int j = 0; j < 4; j++)
                acc[i][j] = __builtin_amdgcn_mfma_f32_16x16x32_bf16(av[i], bv[j], acc[i][j], 0, 0, 0);
    }
    int d0 = db << 7;
    const float* b2e = b2 + (e << 10);
    int colb = wc * 64 + m;
    float vb2[4];
    #pragma unroll
    for (int j = 0; j < 4; j++) vb2[j] = b2e[d0 + colb + j*16];
    const int* rowsE = rows + (e << 13) + mbase;
    const float* gatesE = gates + (e << 13) + mbase;
    int rb = wr * 64 + (q << 2);
    #pragma unroll
    for (int i = 0; i < 4; i++)
        #pragma unroll
        for (int reg = 0; reg < 4; reg++){
            int mr = rb + i*16 + reg;
            if (mbase + mr < Me){
                int token = rowsE[mr];
                float gate = gatesE[mr];
                float* orow = out + ((size_t)token << 10) + d0 + colb;
                #pragma unroll
                for (int j = 0; j < 4; j++)
                    unsafeAtomicAdd(&orow[j*16], gate * (acc[i][j][reg] + vb2[j]));
            }
        }
}

extern "C" void kernel_launch(void* const* d_in, const int* in_sizes, int n_in,
                              void* d_out, int out_size, void* d_ws, size_t ws_size,
                              hipStream_t stream) {
    const float* x  = (const float*)d_in[0];
    const float* Wr = (const float*)d_in[1];
    const float* br = (const float*)d_in[2];
    const float* W1 = (const float*)d_in[3];
    const float* b1 = (const float*)d_in[4];
    const float* W2 = (const float*)d_in[5];
    const float* b2 = (const float*)d_in[6];
    float* out = (float*)d_out;

    char* ws = (char*)d_ws;
    int*   cnt   = (int*)(ws + OFF_CNT);
    float* psum  = (float*)(ws + OFF_PSUM);
    int*   offs  = (int*)(ws + OFF_OFFS);
    int*   rows  = (int*)(ws + OFF_ROWS);
    float* gates = (float*)(ws + OFF_GATES);
    short* xbf   = (short*)(ws + OFF_XBF);
    short* g     = (short*)(ws + OFF_G);
    short* W1s   = (short*)(ws + OFF_W1S);
    short* W2s   = (short*)(ws + OFF_W2S);

    hipMemsetAsync(ws, 0, 192, stream);
    hipMemsetAsync(d_out, 0, (size_t)NTOK * DIM * 4, stream);

    prep_w<<<dim3(32, 32, 8), 256, 0, stream>>>(W1, W1s, 1024, 4096);
    prep_w<<<dim3(64, 8, 8),  256, 0, stream>>>(W2, W2s, 2048, 1024);
    convert_x<<<4096, 256, 0, stream>>>(x, xbf);
    router<<<256, 256, 0, stream>>>(x, Wr, br, cnt, psum, rows, gates);
    finalize_aux<<<1, 64, 0, stream>>>(cnt, psum, offs, out + (size_t)NTOK * DIM);
    gemm1<<<dim3(32, 64, 8), 256, 0, stream>>>(xbf, W1s, b1, cnt, offs, rows, g);
    gemm2<<<dim3(8, 64, 8),  256, 0, stream>>>(g, W2s, b2, cnt, offs, rows, gates, out);
}

// Round 8
// 656.071 us; speedup vs baseline: 1.1872x; 1.0272x over previous
//
#include <hip/hip_runtime.h>
#include <hip/hip_bf16.h>
#include <math.h>

typedef __attribute__((ext_vector_type(8))) __bf16 bh8;   // MFMA A/B frag
typedef __attribute__((ext_vector_type(4))) float  f4;    // MFMA C/D frag

#define NTOK   8192
#define DIM    1024
#define HIDK   2048

// ws layout (bytes)
#define OFF_CNT    0
#define OFF_PSUM   64
#define OFF_OFFS   128
#define OFF_ROWS   512
#define OFF_GATES  (512+262144)
#define OFF_XBF    524800
#define OFF_G      (524800+16777216)          // 16640 x 2048 shorts
#define OFF_W1S    (OFF_G + 68157440)         // 8*4096*1024 shorts (swizzled blobs)
#define OFF_W2S    (OFF_W1S + 67108864)       // 8*1024*2048 shorts

__device__ __forceinline__ unsigned short f2bf(float x){
    union { float f; unsigned u; } v; v.f = x;
    unsigned r = v.u + 0x7FFFu + ((v.u >> 16) & 1u);
    return (unsigned short)(r >> 16);
}
__device__ __forceinline__ unsigned pk2(float a, float b){
    return (unsigned)f2bf(a) | ((unsigned)f2bf(b) << 16);
}
__device__ __forceinline__ void gload_lds16(const void* g, void* l){
    __builtin_amdgcn_global_load_lds((const __attribute__((address_space(1))) void*)g,
                                     (__attribute__((address_space(3))) void*)l, 16, 0, 0);
}
// counted-vmcnt barrier pair (T4): wait for the PREVIOUS tile's 4 loads only,
// leaving the 4 just-issued in flight across the barrier. "memory" clobber
// pins both the stage intrinsics and the LDS reads on their side of the fence.
#define WAITBAR_PREV() asm volatile("s_waitcnt vmcnt(4)\n\ts_barrier" ::: "memory")
#define WAITBAR_ALL()  asm volatile("s_waitcnt vmcnt(0)\n\ts_barrier" ::: "memory")
#define BAR_ONLY()     asm volatile("s_barrier" ::: "memory")

// ---------- x fp32 -> bf16 ----------
__global__ void convert_x(const float* __restrict__ x, short* __restrict__ xbf){
    size_t i = ((size_t)blockIdx.x * 256 + threadIdx.x) * 8;
    const float4* s = (const float4*)(x + i);
    float4 a = s[0], b = s[1];
    uint4 u;
    u.x = pk2(a.x, a.y); u.y = pk2(a.z, a.w);
    u.z = pk2(b.x, b.y); u.w = pk2(b.z, b.w);
    *(uint4*)(xbf + i) = u;
}

// ---------- weights: [e][K][N] fp32 -> swizzled bf16 blobs [e][N/128][K/32][4096 shorts] ----------
// blob slot s (16B) holds col nl=s>>2, k-chunk c = (s&3) ^ (nl&3) ^ ((nl>>2)&3), k = kb*32+c*8+0..7
__global__ void prep_w(const float* __restrict__ W, short* __restrict__ Ws,
                       int Kdim, int Ndim){
    int kb = blockIdx.x, nb = blockIdx.y, e = blockIdx.z;
    int KB = Kdim >> 5, NB = Ndim >> 7;
    __shared__ float tile[32 * 132];   // [k][n], pad 132
    int t = threadIdx.x;
    const float* src = W + ((size_t)(e * Kdim + kb * 32)) * Ndim + (size_t)nb * 128;
    #pragma unroll
    for (int l = 0; l < 4; l++){
        int flat = (l * 256 + t) * 4;
        int k = flat >> 7, n = flat & 127;
        float4 v = *(const float4*)(src + (size_t)k * Ndim + n);
        float* d = &tile[k * 132 + n];
        d[0] = v.x; d[1] = v.y; d[2] = v.z; d[3] = v.w;
    }
    __syncthreads();
    short* dst = Ws + (((size_t)(e * NB + nb)) * KB + kb) * 4096;
    uint out[8];
    #pragma unroll
    for (int sl = 0; sl < 2; sl++){
        int s = t * 2 + sl;
        int nl = s >> 2, pos = s & 3;
        int c = pos ^ (nl & 3) ^ ((nl >> 2) & 3);
        #pragma unroll
        for (int jj = 0; jj < 4; jj++){
            float a = tile[(c * 8 + jj * 2) * 132 + nl];
            float b = tile[(c * 8 + jj * 2 + 1) * 132 + nl];
            out[sl * 4 + jj] = pk2(a, b);
        }
    }
    *(uint4*)(dst + t * 16)     = *(uint4*)&out[0];
    *(uint4*)(dst + t * 16 + 8) = *(uint4*)&out[4];
}

// ---------- router ----------
__global__ void router(const float* __restrict__ x, const float* __restrict__ Wr,
                       const float* __restrict__ br,
                       int* cnt, float* psum, int* rows, float* gates){
    __shared__ float pP[8];
    __shared__ int   tE[32][2];
    __shared__ float tS[32][2];
    __shared__ int   lcnt[8], lpos[64], lexp[64], gbase[8];
    int t = threadIdx.x, lane = t & 63, w = t >> 6;
    if (t < 8){ pP[t] = 0.f; lcnt[t] = 0; }
    __syncthreads();
    int n0 = blockIdx.x * 32 + w * 8;
    for (int tk = 0; tk < 8; tk++){
        int n = n0 + tk;
        float acc[8] = {0,0,0,0,0,0,0,0};
        const float* xr = x + (size_t)n * DIM;
        for (int d = lane; d < DIM; d += 64){
            float xv = xr[d];
            const float* wrow = Wr + d * 8;
            #pragma unroll
            for (int e = 0; e < 8; e++) acc[e] += xv * wrow[e];
        }
        #pragma unroll
        for (int e = 0; e < 8; e++){
            float v = acc[e];
            v += __shfl_xor(v, 32); v += __shfl_xor(v, 16); v += __shfl_xor(v, 8);
            v += __shfl_xor(v, 4);  v += __shfl_xor(v, 2);  v += __shfl_xor(v, 1);
            acc[e] = v;
        }
        if (lane == 0){
            float l[8], ex[8], m = -1e30f;
            #pragma unroll
            for (int e = 0; e < 8; e++){ l[e] = acc[e] + br[e]; m = fmaxf(m, l[e]); }
            float s = 0.f;
            #pragma unroll
            for (int e = 0; e < 8; e++){ ex[e] = expf(l[e] - m); s += ex[e]; }
            float inv = 1.f / s;
            #pragma unroll
            for (int e = 0; e < 8; e++) atomicAdd(&pP[e], ex[e] * inv);
            int i0 = 0; float v0 = l[0];
            #pragma unroll
            for (int e = 1; e < 8; e++) if (l[e] > v0){ v0 = l[e]; i0 = e; }
            int i1 = -1; float v1 = -1e30f;
            #pragma unroll
            for (int e = 0; e < 8; e++) if (e != i0 && l[e] > v1){ v1 = l[e]; i1 = e; }
            float s0 = 1.f / (1.f + expf(v1 - v0));
            int ti = w * 8 + tk;
            tE[ti][0] = i0; tE[ti][1] = i1;
            tS[ti][0] = s0; tS[ti][1] = 1.f - s0;
        }
    }
    __syncthreads();
    if (t < 64){
        int e = tE[t >> 1][t & 1];
        lexp[t] = e;
        lpos[t] = atomicAdd(&lcnt[e], 1);
    }
    __syncthreads();
    if (t < 8){
        gbase[t] = atomicAdd(&cnt[t], lcnt[t]);
        atomicAdd(&psum[t], pP[t]);
    }
    __syncthreads();
    if (t < 64){
        int e = lexp[t];
        int p = gbase[e] + lpos[t];
        int n = blockIdx.x * 32 + (t >> 1);
        rows[e * NTOK + p]  = n;
        gates[e * NTOK + p] = tS[t >> 1][t & 1];
    }
}

__global__ void finalize_aux(const int* cnt, const float* psum, int* offs, float* out_aux){
    if (threadIdx.x == 0){
        int off = 0; float aux = 0.f;
        for (int e = 0; e < 8; e++){
            offs[e] = off; off += cnt[e];
            aux += ((float)cnt[e] * (1.f/8192.f)) * (psum[e] * (1.f/8192.f));
        }
        out_aux[0] = 8.f * aux;
    }
}

// ---------- GEMM1: 128 rows x 64 g-cols, 256 thr, 4 waves ----------
// r7 skeleton + T3/T4: LDS double-buffer, counted vmcnt(4) barrier (never drain-0
// in the main loop). Per iter: STAGE(buf^1) -> vmcnt(4)+bar -> ds_read/MFMA(buf)
// -> bar. The previous tile's loads complete during this tile's compute.
__global__ __launch_bounds__(256, 4) void gemm1(
    const short* __restrict__ xbf, const short* __restrict__ W1s,
    const float* __restrict__ b1, const int* __restrict__ cnt,
    const int* __restrict__ offs, const int* __restrict__ rows,
    short* __restrict__ g)
{
    int e = blockIdx.z;
    int Me = cnt[e];
    int mbase = blockIdx.y << 7;
    if (mbase >= Me) return;
    int xB = blockIdx.x;                 // 0..31 -> g-cols xB*64
    __shared__ short As [2][4096];       // 16KB (2 x 128x32)
    __shared__ short Bsa[2][2048];       // 8KB
    __shared__ short Bsb[2][2048];       // 8KB

    int t = threadIdx.x, lane = t & 63, w = t >> 6;
    int wr = w & 1, wc = w >> 1;
    int m = lane & 15, q = lane >> 4;
    int sw8 = (q ^ (m & 3) ^ ((m >> 2) & 3)) << 3;

    const int* rowsE = rows + (e << 13) + mbase;
    int r = t >> 2, pos = t & 3;
    int ca = pos ^ (r & 3) ^ ((r >> 2) & 3);
    int tok0 = (mbase + r      < Me) ? rowsE[r]      : 0;
    int tok1 = (mbase + r + 64 < Me) ? rowsE[r + 64] : 0;
    const short* ga0 = xbf + ((size_t)tok0 << 10) + (ca << 3);
    const short* ga1 = xbf + ((size_t)tok1 << 10) + (ca << 3);
    int ha = xB & 1, nb128 = xB >> 1;
    const short* gb0 = W1s + ((size_t)((e * 32 + nb128)      * 32)) * 4096 + (ha * 256 + t) * 8;
    const short* gb1 = W1s + ((size_t)((e * 32 + 16 + nb128) * 32)) * 4096 + (ha * 256 + t) * 8;
    short* ldsA0 = &As [0][w * 512];         // rows 0..63 chunk for this wave
    short* ldsA1 = &As [0][2048 + w * 512];  // rows 64..127
    short* ldsBa = &Bsa[0][w * 512];
    short* ldsBb = &Bsb[0][w * 512];

    f4 acc_a[4][2], acc_b[4][2];
    f4 zz = {0.f,0.f,0.f,0.f};
    #pragma unroll
    for (int i = 0; i < 4; i++)
        #pragma unroll
        for (int j = 0; j < 2; j++){ acc_a[i][j] = zz; acc_b[i][j] = zz; }

    // prologue: stage tile 0 into buf 0 (4 outstanding loads/wave)
    gload_lds16(ga0, ldsA0);
    gload_lds16(ga1, ldsA1);
    gload_lds16(gb0, ldsBa);
    gload_lds16(gb1, ldsBb);
    ga0 += 32; ga1 += 32; gb0 += 4096; gb1 += 4096;

    int cur = 0;
    #pragma unroll 2
    for (int k0 = 0; k0 < DIM - 32; k0 += 32){
        int nxt = cur ^ 1;
        // stage next tile into buf[nxt] (now 8 outstanding)
        gload_lds16(ga0, ldsA0 + nxt * 4096);
        gload_lds16(ga1, ldsA1 + nxt * 4096);
        gload_lds16(gb0, ldsBa + nxt * 2048);
        gload_lds16(gb1, ldsBb + nxt * 2048);
        ga0 += 32; ga1 += 32; gb0 += 4096; gb1 += 4096;
        WAITBAR_PREV();   // wait current tile's 4 loads; next tile's stay in flight
        bh8 av[4], ba[2], bb[2];
        #pragma unroll
        for (int i = 0; i < 4; i++)
            av[i] = *(const bh8*)&As[cur][(wr*64 + i*16 + m) * 32 + sw8];
        #pragma unroll
        for (int j = 0; j < 2; j++){
            int nn = ((wc << 5) + j*16 + m) * 32 + sw8;
            ba[j] = *(const bh8*)&Bsa[cur][nn];
            bb[j] = *(const bh8*)&Bsb[cur][nn];
        }
        #pragma unroll
        for (int i = 0; i < 4; i++)
            #pragma unroll
            for (int j = 0; j < 2; j++){
                acc_a[i][j] = __builtin_amdgcn_mfma_f32_16x16x32_bf16(av[i], ba[j], acc_a[i][j], 0, 0, 0);
                acc_b[i][j] = __builtin_amdgcn_mfma_f32_16x16x32_bf16(av[i], bb[j], acc_b[i][j], 0, 0, 0);
            }
        BAR_ONLY();       // all reads of buf[cur] done -> next iter may overwrite it
        cur = nxt;
    }
    // epilogue tile (no prefetch): drain remaining 4 loads
    WAITBAR_ALL();
    {
        bh8 av[4], ba[2], bb[2];
        #pragma unroll
        for (int i = 0; i < 4; i++)
            av[i] = *(const bh8*)&As[cur][(wr*64 + i*16 + m) * 32 + sw8];
        #pragma unroll
        for (int j = 0; j < 2; j++){
            int nn = ((wc << 5) + j*16 + m) * 32 + sw8;
            ba[j] = *(const bh8*)&Bsa[cur][nn];
            bb[j] = *(const bh8*)&Bsb[cur][nn];
        }
        #pragma unroll
        for (int i = 0; i < 4; i++)
            #pragma unroll
            for (int j = 0; j < 2; j++){
                acc_a[i][j] = __builtin_amdgcn_mfma_f32_16x16x32_bf16(av[i], ba[j], acc_a[i][j], 0, 0, 0);
                acc_b[i][j] = __builtin_amdgcn_mfma_f32_16x16x32_bf16(av[i], bb[j], acc_b[i][j], 0, 0, 0);
            }
    }
    int c0 = xB << 6;
    const float* b1e = b1 + (e << 12);
    int colb = (wc << 5) + m;
    float vba[2], vbb[2];
    #pragma unroll
    for (int j = 0; j < 2; j++){
        vba[j] = b1e[c0 + colb + j*16];
        vbb[j] = b1e[HIDK + c0 + colb + j*16];
    }
    int rb = wr * 64 + (q << 2);
    short* gE = g + ((size_t)(offs[e] + mbase)) * HIDK;
    #pragma unroll
    for (int i = 0; i < 4; i++)
        #pragma unroll
        for (int reg = 0; reg < 4; reg++){
            int mr = rb + i*16 + reg;
            if (mbase + mr < Me){
                short* grow = gE + (size_t)mr * HIDK + c0 + colb;
                #pragma unroll
                for (int j = 0; j < 2; j++){
                    float va = acc_a[i][j][reg] + vba[j];
                    float vb = acc_b[i][j][reg] + vbb[j];
                    grow[j*16] = (short)f2bf(va / (1.f + __expf(-va)) * vb);
                }
            }
        }
}

// ---------- GEMM2: 128 rows x 128 out-cols, 256 thr, 4 waves (wave 64x64) ----------
// same counted-vmcnt double-buffer pipeline
__global__ __launch_bounds__(256, 4) void gemm2(
    const short* __restrict__ g, const short* __restrict__ W2s,
    const float* __restrict__ b2, const int* __restrict__ cnt,
    const int* __restrict__ offs, const int* __restrict__ rows,
    const float* __restrict__ gates, float* __restrict__ out)
{
    int e = blockIdx.z;
    int Me = cnt[e];
    int mbase = blockIdx.y << 7;
    if (mbase >= Me) return;
    int db = blockIdx.x;                 // 0..7
    __shared__ short As[2][4096];        // 16KB
    __shared__ short Bs[2][4096];        // 16KB

    int t = threadIdx.x, lane = t & 63, w = t >> 6;
    int wr = w & 1, wc = w >> 1;
    int m = lane & 15, q = lane >> 4;
    int sw8 = (q ^ (m & 3) ^ ((m >> 2) & 3)) << 3;

    int gbaseR = offs[e] + mbase;
    int r = t >> 2;
    int ca = (t & 3) ^ (r & 3) ^ ((r >> 2) & 3);
    const short* ga0 = g + ((size_t)(gbaseR + r))      * HIDK + (ca << 3);
    const short* ga1 = g + ((size_t)(gbaseR + r + 64)) * HIDK + (ca << 3);
    const short* gb0 = W2s + ((size_t)((e * 8 + db) * 64)) * 4096 + t * 8;
    const short* gb1 = gb0 + 2048;       // slots 256..511 (cols 64..127)
    short* ldsA0 = &As[0][w * 512];
    short* ldsA1 = &As[0][2048 + w * 512];
    short* ldsB0 = &Bs[0][w * 512];
    short* ldsB1 = &Bs[0][2048 + w * 512];

    f4 acc[4][4];
    f4 zz = {0.f,0.f,0.f,0.f};
    #pragma unroll
    for (int i = 0; i < 4; i++)
        #pragma unroll
        for (int j = 0; j < 4; j++) acc[i][j] = zz;

    // prologue: stage tile 0 into buf 0
    gload_lds16(ga0, ldsA0);
    gload_lds16(ga1, ldsA1);
    gload_lds16(gb0, ldsB0);
    gload_lds16(gb1, ldsB1);
    ga0 += 32; ga1 += 32; gb0 += 4096; gb1 += 4096;

    int cur = 0;
    #pragma unroll 2
    for (int k0 = 0; k0 < HIDK - 32; k0 += 32){
        int nxt = cur ^ 1;
        gload_lds16(ga0, ldsA0 + nxt * 4096);
        gload_lds16(ga1, ldsA1 + nxt * 4096);
        gload_lds16(gb0, ldsB0 + nxt * 4096);
        gload_lds16(gb1, ldsB1 + nxt * 4096);
        ga0 += 32; ga1 += 32; gb0 += 4096; gb1 += 4096;
        WAITBAR_PREV();
        bh8 av[4], bv[4];
        #pragma unroll
        for (int i = 0; i < 4; i++)
            av[i] = *(const bh8*)&As[cur][(wr*64 + i*16 + m) * 32 + sw8];
        #pragma unroll
        for (int j = 0; j < 4; j++)
            bv[j] = *(const bh8*)&Bs[cur][(wc*64 + j*16 + m) * 32 + sw8];
        #pragma unroll
        for (int i = 0; i < 4; i++)
            #pragma unroll
            for (int j = 0; j < 4; j++)
                acc[i][j] = __builtin_amdgcn_mfma_f32_16x16x32_bf16(av[i], bv[j], acc[i][j], 0, 0, 0);
        BAR_ONLY();
        cur = nxt;
    }
    WAITBAR_ALL();
    {
        bh8 av[4], bv[4];
        #pragma unroll
        for (int i = 0; i < 4; i++)
            av[i] = *(const bh8*)&As[cur][(wr*64 + i*16 + m) * 32 + sw8];
        #pragma unroll
        for (int j = 0; j < 4; j++)
            bv[j] = *(const bh8*)&Bs[cur][(wc*64 + j*16 + m) * 32 + sw8];
        #pragma unroll
        for (int i = 0; i < 4; i++)
            #pragma unroll
            for (int j = 0; j < 4; j++)
                acc[i][j] = __builtin_amdgcn_mfma_f32_16x16x32_bf16(av[i], bv[j], acc[i][j], 0, 0, 0);
    }
    int d0 = db << 7;
    const float* b2e = b2 + (e << 10);
    int colb = wc * 64 + m;
    float vb2[4];
    #pragma unroll
    for (int j = 0; j < 4; j++) vb2[j] = b2e[d0 + colb + j*16];
    const int* rowsE = rows + (e << 13) + mbase;
    const float* gatesE = gates + (e << 13) + mbase;
    int rb = wr * 64 + (q << 2);
    #pragma unroll
    for (int i = 0; i < 4; i++)
        #pragma unroll
        for (int reg = 0; reg < 4; reg++){
            int mr = rb + i*16 + reg;
            if (mbase + mr < Me){
                int token = rowsE[mr];
                float gate = gatesE[mr];
                float* orow = out + ((size_t)token << 10) + d0 + colb;
                #pragma unroll
                for (int j = 0; j < 4; j++)
                    unsafeAtomicAdd(&orow[j*16], gate * (acc[i][j][reg] + vb2[j]));
            }
        }
}

extern "C" void kernel_launch(void* const* d_in, const int* in_sizes, int n_in,
                              void* d_out, int out_size, void* d_ws, size_t ws_size,
                              hipStream_t stream) {
    const float* x  = (const float*)d_in[0];
    const float* Wr = (const float*)d_in[1];
    const float* br = (const float*)d_in[2];
    const float* W1 = (const float*)d_in[3];
    const float* b1 = (const float*)d_in[4];
    const float* W2 = (const float*)d_in[5];
    const float* b2 = (const float*)d_in[6];
    float* out = (float*)d_out;

    char* ws = (char*)d_ws;
    int*   cnt   = (int*)(ws + OFF_CNT);
    float* psum  = (float*)(ws + OFF_PSUM);
    int*   offs  = (int*)(ws + OFF_OFFS);
    int*   rows  = (int*)(ws + OFF_ROWS);
    float* gates = (float*)(ws + OFF_GATES);
    short* xbf   = (short*)(ws + OFF_XBF);
    short* g     = (short*)(ws + OFF_G);
    short* W1s   = (short*)(ws + OFF_W1S);
    short* W2s   = (short*)(ws + OFF_W2S);

    hipMemsetAsync(ws, 0, 192, stream);
    hipMemsetAsync(d_out, 0, (size_t)NTOK * DIM * 4, stream);

    prep_w<<<dim3(32, 32, 8), 256, 0, stream>>>(W1, W1s, 1024, 4096);
    prep_w<<<dim3(64, 8, 8),  256, 0, stream>>>(W2, W2s, 2048, 1024);
    convert_x<<<4096, 256, 0, stream>>>(x, xbf);
    router<<<256, 256, 0, stream>>>(x, Wr, br, cnt, psum, rows, gates);
    finalize_aux<<<1, 64, 0, stream>>>(cnt, psum, offs, out + (size_t)NTOK * DIM);
    gemm1<<<dim3(32, 64, 8), 256, 0, stream>>>(xbf, W1s, b1, cnt, offs, rows, g);
    gemm2<<<dim3(8, 64, 8),  256, 0, stream>>>(g, W2s, b2, cnt, offs, rows, gates, out);
}